// Round 4
// baseline (7014.491 us; speedup 1.0000x reference)
//
#include <hip/hip_runtime.h>
#include <math.h>

#define SEQL 2048
#define H 1024
#define G3 3072
#define SENT 1.0e30f

__device__ __forceinline__ float sigmoidf_(float x){ return 1.0f/(1.0f+expf(-x)); }

// Cache-bypassing (sc0 sc1) 16B load: always served from coherence point.
__device__ __forceinline__ float4 ld_cohere4(const float* p){
  float4 r;
  asm volatile("global_load_dwordx4 %0, %1, off sc0 sc1\n\t"
               "s_waitcnt vmcnt(0)"
               : "=&v"(r) : "v"(p) : "memory");
  return r;
}
// Cache-bypassing 4B store: immediately visible at coherence point.
__device__ __forceinline__ void st_cohere1(float* p, float v){
  asm volatile("global_store_dword %0, %1, off sc0 sc1"
               :: "v"(p), "v"(v) : "memory");
}

// Fill h-exchange buffers with sentinel each call (graph-replay safe).
__global__ __launch_bounds__(256) void init_sent(float* p, int n4){
  int i = blockIdx.x*256 + threadIdx.x;
  if (i < n4) ((float4*)p)[i] = make_float4(SENT,SENT,SENT,SENT);
}

// embeds[t] = (ids[t]==1) ? 0 : embedding[ids[t]]
__global__ __launch_bounds__(256) void embed_kernel(const int* __restrict__ ids,
                                                    const float* __restrict__ emb,
                                                    float* __restrict__ out){
  int t = blockIdx.x;
  int id = ids[t];
  const float4* src = (const float4*)(emb + (size_t)id*H);
  float4* dst = (float4*)(out + (size_t)t*H);
  float4 v = (id == 1) ? make_float4(0.f,0.f,0.f,0.f) : src[threadIdx.x];
  dst[threadIdx.x] = v;
}

// C = A(2048x1024) * B^T + bias, B is 3072x1024 row-major (fwd blocks, then rev).
__global__ __launch_bounds__(256) void gemm_kernel(const float* __restrict__ A,
  const float* __restrict__ WF, const float* __restrict__ WR,
  const float* __restrict__ bF, const float* __restrict__ bR,
  float* __restrict__ gxF, float* __restrict__ gxR)
{
  __shared__ float As[16][68];
  __shared__ float Bs[16][68];
  const int tid = threadIdx.x;
  const int n0 = blockIdx.x * 64;
  const int m0 = blockIdx.y * 64;
  const int dir = (n0 >= G3);
  const float* B    = dir ? WR : WF;
  const float* bias = dir ? bR : bF;
  float* C          = dir ? gxR : gxF;
  const int j0 = dir ? (n0 - G3) : n0;

  const int lr = tid >> 2;
  const int lc = (tid & 3) * 4;
  const int tx = tid & 15;
  const int ty = tid >> 4;

  float acc[4][4] = {};

  for (int k0 = 0; k0 < H; k0 += 16){
    float4 av = *(const float4*)(A + (size_t)(m0+lr)*H + k0 + lc);
    float4 bv = *(const float4*)(B + (size_t)(j0+lr)*H + k0 + lc);
    As[lc+0][lr]=av.x; As[lc+1][lr]=av.y; As[lc+2][lr]=av.z; As[lc+3][lr]=av.w;
    Bs[lc+0][lr]=bv.x; Bs[lc+1][lr]=bv.y; Bs[lc+2][lr]=bv.z; Bs[lc+3][lr]=bv.w;
    __syncthreads();
    #pragma unroll
    for (int kk=0; kk<16; ++kk){
      float a0=As[kk][ty*4+0], a1=As[kk][ty*4+1], a2=As[kk][ty*4+2], a3=As[kk][ty*4+3];
      float b0=Bs[kk][tx*4+0], b1=Bs[kk][tx*4+1], b2=Bs[kk][tx*4+2], b3=Bs[kk][tx*4+3];
      acc[0][0]=fmaf(a0,b0,acc[0][0]); acc[0][1]=fmaf(a0,b1,acc[0][1]);
      acc[0][2]=fmaf(a0,b2,acc[0][2]); acc[0][3]=fmaf(a0,b3,acc[0][3]);
      acc[1][0]=fmaf(a1,b0,acc[1][0]); acc[1][1]=fmaf(a1,b1,acc[1][1]);
      acc[1][2]=fmaf(a1,b2,acc[1][2]); acc[1][3]=fmaf(a1,b3,acc[1][3]);
      acc[2][0]=fmaf(a2,b0,acc[2][0]); acc[2][1]=fmaf(a2,b1,acc[2][1]);
      acc[2][2]=fmaf(a2,b2,acc[2][2]); acc[2][3]=fmaf(a2,b3,acc[2][3]);
      acc[3][0]=fmaf(a3,b0,acc[3][0]); acc[3][1]=fmaf(a3,b1,acc[3][1]);
      acc[3][2]=fmaf(a3,b2,acc[3][2]); acc[3][3]=fmaf(a3,b3,acc[3][3]);
    }
    __syncthreads();
  }

  #pragma unroll
  for (int u=0; u<4; ++u){
    float4 o;
    o.x = acc[u][0] + bias[j0+tx*4+0];
    o.y = acc[u][1] + bias[j0+tx*4+1];
    o.z = acc[u][2] + bias[j0+tx*4+2];
    o.w = acc[u][3] + bias[j0+tx*4+3];
    *(float4*)(C + (size_t)(m0+ty*4+u)*G3 + j0 + tx*4) = o;
  }
}

// Persistent scan: 256 WGs x 512 threads (128 WG/dir). Each wave owns one
// h-element (3 W_hh rows = 48 weight floats/lane), held in AGPRs — the
// allocator has no occupancy reason to spill them (R3 showed VGPR heuristics
// spill "+v"-pinned VGPR arrays to scratch). Per-step AGPR->VGPR pulls are
// h-independent and hide under the poll. h exchange: sc0/sc1 bypass +
// sentinel poll, dwordx4 granules (halves fabric transactions vs R3).
// Fragment mapping: k(q,j) = q*256 + lane*4 + j for both weights and h.
__global__ __launch_bounds__(512, 1) void scan_kernel(
  const float* __restrict__ gxF, const float* __restrict__ gxR,
  const float* __restrict__ WhF, const float* __restrict__ WhR,
  const float* __restrict__ bhF, const float* __restrict__ bhR,
  float* hFbuf, float* hRbuf, float* __restrict__ out)
{
  const int wgid = blockIdx.x;        // 0..255
  const int dir  = wgid >> 7;         // 0 fwd, 1 rev
  const int d    = wgid & 127;        // chunk id
  const int i0   = d * 8;
  const int tid  = threadIdx.x;       // 0..511
  const int lane = tid & 63;
  const int wv   = tid >> 6;          // wave 0..7

  const float* gx  = dir ? gxR : gxF;
  const float* Whh = dir ? WhR : WhF;
  const float* bhh = dir ? bhR : bhF;
  float* hbuf      = dir ? hRbuf : hFbuf;

  const int ia = i0 + wv;             // this wave's h-element
  const int rows[3] = { ia, H+ia, 2*H+ia };

  // Load weights (chunked-k mapping) and park them in AGPRs.
  float wa[48];
  float bias[3];
  #pragma unroll
  for (int rr=0; rr<3; ++rr){
    bias[rr] = bhh[rows[rr]];
    const float* wp = Whh + (size_t)rows[rr]*H;
    #pragma unroll
    for (int q=0; q<4; ++q){
      float4 w4 = *(const float4*)(wp + q*256 + lane*4);
      asm volatile("v_accvgpr_write_b32 %0, %1" : "=a"(wa[rr*16+q*4+0]) : "v"(w4.x));
      asm volatile("v_accvgpr_write_b32 %0, %1" : "=a"(wa[rr*16+q*4+1]) : "v"(w4.y));
      asm volatile("v_accvgpr_write_b32 %0, %1" : "=a"(wa[rr*16+q*4+2]) : "v"(w4.z));
      asm volatile("v_accvgpr_write_b32 %0, %1" : "=a"(wa[rr*16+q*4+3]) : "v"(w4.w));
    }
  }

  __shared__ float hs[2][H];          // double buffer -> single barrier/step

  for (int s=0; s<SEQL; ++s){
    const int b = s & 1;
    const int t = dir ? (SEQL-1-s) : s;
    const float* gxt = gx + (size_t)t*G3;
    // h-independent work issued before the poll: gx loads + weight pulls
    float g0 = gxt[ia], g1 = gxt[H+ia], g2 = gxt[2*H+ia];
    float wr[48];
    #pragma unroll
    for (int i=0; i<48; ++i)
      asm volatile("v_accvgpr_read_b32 %0, %1" : "=v"(wr[i]) : "a"(wa[i]));

    if (tid < 256){
      float4* dst = (float4*)&hs[b][tid*4];
      if (s == 0){
        *dst = make_float4(0.f,0.f,0.f,0.f);
      } else {
        const float* src = hbuf + (size_t)(s-1)*H + tid*4;
        float4 v;
        do { v = ld_cohere4(src); }
        while (v.x==SENT || v.y==SENT || v.z==SENT || v.w==SENT);
        *dst = v;
      }
    }
    __syncthreads();

    float hv[16];
    #pragma unroll
    for (int q=0; q<4; ++q){
      float4 hq = *(const float4*)&hs[b][q*256 + lane*4];
      hv[q*4+0]=hq.x; hv[q*4+1]=hq.y; hv[q*4+2]=hq.z; hv[q*4+3]=hq.w;
    }

    float dots[3];
    #pragma unroll
    for (int rr=0; rr<3; ++rr){
      float acc = 0.f;
      #pragma unroll
      for (int m=0; m<16; ++m) acc = fmaf(wr[rr*16+m], hv[m], acc);
      #pragma unroll
      for (int off=32; off>0; off>>=1) acc += __shfl_xor(acc, off);
      dots[rr] = acc + bias[rr];
    }

    const float hp = hs[b][ia];
    float r = sigmoidf_(g0 + dots[0]);
    float z = sigmoidf_(g1 + dots[1]);
    float n = tanhf    (g2 + r*dots[2]);
    float hn = (1.f - z)*n + z*hp;

    if (lane == 0){
      st_cohere1(hbuf + (size_t)s*H + ia, hn);   // unblock consumers first
      out[(size_t)t*2048 + dir*H + ia] = hn;
      if (s == SEQL-1){
        const size_t base = (size_t)SEQL*2048;
        out[base + dir*H + ia]        = hn;   // hidden
        out[base + 2048 + dir*H + ia] = hn;   // projected_output
      }
    }
    // no trailing barrier: next step's pollers write hs[b^1]
  }
}

extern "C" void kernel_launch(void* const* d_in, const int* in_sizes, int n_in,
                              void* d_out, int out_size, void* d_ws, size_t ws_size,
                              hipStream_t stream)
{
  const int*   ids  = (const int*)  d_in[0];
  const float* emb  = (const float*)d_in[1];
  const float* WihF = (const float*)d_in[2];
  const float* WhhF = (const float*)d_in[3];
  const float* bihF = (const float*)d_in[4];
  const float* bhhF = (const float*)d_in[5];
  const float* WihR = (const float*)d_in[6];
  const float* WhhR = (const float*)d_in[7];
  const float* bihR = (const float*)d_in[8];
  const float* bhhR = (const float*)d_in[9];
  float* out = (float*)d_out;
  float* ws  = (float*)d_ws;

  float* embeds = ws;                       // 2048*1024
  float* gxF    = embeds + (size_t)SEQL*H;  // 2048*3072
  float* gxR    = gxF + (size_t)SEQL*G3;    // 2048*3072
  float* hF     = gxR + (size_t)SEQL*G3;    // 2048*1024
  float* hR     = hF + (size_t)SEQL*H;      // 2048*1024

  init_sent<<<4096, 256, 0, stream>>>(hF, 1048576);
  embed_kernel<<<SEQL, 256, 0, stream>>>(ids, emb, embeds);
  dim3 gg(96, 32);
  gemm_kernel<<<gg, 256, 0, stream>>>(embeds, WihF, WihR, bihF, bihR, gxF, gxR);
  scan_kernel<<<256, 512, 0, stream>>>(gxF, gxR, WhhF, WhhR, bhhF, bhhR, hF, hR, out);
}

// Round 6
// 6409.286 us; speedup vs baseline: 1.0944x; 1.0944x over previous
//
#include <hip/hip_runtime.h>
#include <math.h>

#define SEQL 2048
#define H 1024
#define G3 3072

__device__ __forceinline__ float sigmoidf_(float x){ return 1.0f/(1.0f+expf(-x)); }

// Cache-bypassing (sc0 sc1) 16B load from coherence point.
__device__ __forceinline__ float4 ld_cohere4(const float* p){
  float4 r;
  asm volatile("global_load_dwordx4 %0, %1, off sc0 sc1\n\t"
               "s_waitcnt vmcnt(0)"
               : "=&v"(r) : "v"(p) : "memory");
  return r;
}
__device__ __forceinline__ int ld_ctr(const int* p){
  int r;
  asm volatile("global_load_dword %0, %1, off sc0 sc1\n\t"
               "s_waitcnt vmcnt(0)"
               : "=&v"(r) : "v"(p) : "memory");
  return r;
}
// Cache-bypassing 8B store (float2 input constraint is supported; float4 is not).
__device__ __forceinline__ void st_cohere2(float* p, float2 v){
  asm volatile("global_store_dwordx2 %0, %1, off sc0 sc1"
               :: "v"(p), "v"(v) : "memory");
}

// Zero the readiness-counter region each call (graph-replay safe).
__global__ __launch_bounds__(256) void init_zero(int* p, int n4){
  int i = blockIdx.x*256 + threadIdx.x;
  if (i < n4) ((int4*)p)[i] = make_int4(0,0,0,0);
}

// embeds[t] = (ids[t]==1) ? 0 : embedding[ids[t]]
__global__ __launch_bounds__(256) void embed_kernel(const int* __restrict__ ids,
                                                    const float* __restrict__ emb,
                                                    float* __restrict__ out){
  int t = blockIdx.x;
  int id = ids[t];
  const float4* src = (const float4*)(emb + (size_t)id*H);
  float4* dst = (float4*)(out + (size_t)t*H);
  float4 v = (id == 1) ? make_float4(0.f,0.f,0.f,0.f) : src[threadIdx.x];
  dst[threadIdx.x] = v;
}

// C = A(2048x1024) * B^T + bias, B is 3072x1024 row-major (fwd blocks, then rev).
__global__ __launch_bounds__(256) void gemm_kernel(const float* __restrict__ A,
  const float* __restrict__ WF, const float* __restrict__ WR,
  const float* __restrict__ bF, const float* __restrict__ bR,
  float* __restrict__ gxF, float* __restrict__ gxR)
{
  __shared__ float As[16][68];
  __shared__ float Bs[16][68];
  const int tid = threadIdx.x;
  const int n0 = blockIdx.x * 64;
  const int m0 = blockIdx.y * 64;
  const int dir = (n0 >= G3);
  const float* B    = dir ? WR : WF;
  const float* bias = dir ? bR : bF;
  float* C          = dir ? gxR : gxF;
  const int j0 = dir ? (n0 - G3) : n0;

  const int lr = tid >> 2;
  const int lc = (tid & 3) * 4;
  const int tx = tid & 15;
  const int ty = tid >> 4;

  float acc[4][4] = {};

  for (int k0 = 0; k0 < H; k0 += 16){
    float4 av = *(const float4*)(A + (size_t)(m0+lr)*H + k0 + lc);
    float4 bv = *(const float4*)(B + (size_t)(j0+lr)*H + k0 + lc);
    As[lc+0][lr]=av.x; As[lc+1][lr]=av.y; As[lc+2][lr]=av.z; As[lc+3][lr]=av.w;
    Bs[lc+0][lr]=bv.x; Bs[lc+1][lr]=bv.y; Bs[lc+2][lr]=bv.z; Bs[lc+3][lr]=bv.w;
    __syncthreads();
    #pragma unroll
    for (int kk=0; kk<16; ++kk){
      float a0=As[kk][ty*4+0], a1=As[kk][ty*4+1], a2=As[kk][ty*4+2], a3=As[kk][ty*4+3];
      float b0=Bs[kk][tx*4+0], b1=Bs[kk][tx*4+1], b2=Bs[kk][tx*4+2], b3=Bs[kk][tx*4+3];
      acc[0][0]=fmaf(a0,b0,acc[0][0]); acc[0][1]=fmaf(a0,b1,acc[0][1]);
      acc[0][2]=fmaf(a0,b2,acc[0][2]); acc[0][3]=fmaf(a0,b3,acc[0][3]);
      acc[1][0]=fmaf(a1,b0,acc[1][0]); acc[1][1]=fmaf(a1,b1,acc[1][1]);
      acc[1][2]=fmaf(a1,b2,acc[1][2]); acc[1][3]=fmaf(a1,b3,acc[1][3]);
      acc[2][0]=fmaf(a2,b0,acc[2][0]); acc[2][1]=fmaf(a2,b1,acc[2][1]);
      acc[2][2]=fmaf(a2,b2,acc[2][2]); acc[2][3]=fmaf(a2,b3,acc[2][3]);
      acc[3][0]=fmaf(a3,b0,acc[3][0]); acc[3][1]=fmaf(a3,b1,acc[3][1]);
      acc[3][2]=fmaf(a3,b2,acc[3][2]); acc[3][3]=fmaf(a3,b3,acc[3][3]);
    }
    __syncthreads();
  }

  #pragma unroll
  for (int u=0; u<4; ++u){
    float4 o;
    o.x = acc[u][0] + bias[j0+tx*4+0];
    o.y = acc[u][1] + bias[j0+tx*4+1];
    o.z = acc[u][2] + bias[j0+tx*4+2];
    o.w = acc[u][3] + bias[j0+tx*4+3];
    *(float4*)(C + (size_t)(m0+ty*4+u)*G3 + j0 + tx*4) = o;
  }
}

// Persistent scan, poll-on-flag protocol:
//  producers: 4x dwordx2 sc0sc1 h-chunk stores -> vmcnt(0) -> 1 atomic inc of
//             sub-counter (d&7) for step s (8 lines/step/dir, 16 producers each)
//  consumers: wave0 lanes 0..7 spin on the 8 sub-counter lines; when all ==16,
//             WG issues the 4KB h read ONCE (256 lanes x 16B) into LDS.
// Weights AGPR-parked (no scratch); AGPR pulls + gx loads hoisted above the wait.
__global__ __launch_bounds__(512, 1) void scan_kernel(
  const float* __restrict__ gxF, const float* __restrict__ gxR,
  const float* __restrict__ WhF, const float* __restrict__ WhR,
  const float* __restrict__ bhF, const float* __restrict__ bhR,
  float* hFbuf, float* hRbuf, int* ctrF, int* ctrR,
  float* __restrict__ out)
{
  const int wgid = blockIdx.x;        // 0..255
  const int dir  = wgid >> 7;         // 0 fwd, 1 rev
  const int d    = wgid & 127;        // chunk id
  const int i0   = d * 8;
  const int tid  = threadIdx.x;       // 0..511
  const int lane = tid & 63;
  const int wv   = tid >> 6;          // wave 0..7

  const float* gx  = dir ? gxR : gxF;
  const float* Whh = dir ? WhR : WhF;
  const float* bhh = dir ? bhR : bhF;
  float* hbuf      = dir ? hRbuf : hFbuf;
  int*   ctr       = dir ? ctrR : ctrF;

  const int ia = i0 + wv;             // this wave's h-element
  const int rows[3] = { ia, H+ia, 2*H+ia };

  // Load weights (chunked-k mapping: k = q*256 + lane*4 + j), park in AGPRs.
  float wa[48];
  float bias[3];
  #pragma unroll
  for (int rr=0; rr<3; ++rr){
    bias[rr] = bhh[rows[rr]];
    const float* wp = Whh + (size_t)rows[rr]*H;
    #pragma unroll
    for (int q=0; q<4; ++q){
      float4 w4 = *(const float4*)(wp + q*256 + lane*4);
      asm volatile("v_accvgpr_write_b32 %0, %1" : "=a"(wa[rr*16+q*4+0]) : "v"(w4.x));
      asm volatile("v_accvgpr_write_b32 %0, %1" : "=a"(wa[rr*16+q*4+1]) : "v"(w4.y));
      asm volatile("v_accvgpr_write_b32 %0, %1" : "=a"(wa[rr*16+q*4+2]) : "v"(w4.z));
      asm volatile("v_accvgpr_write_b32 %0, %1" : "=a"(wa[rr*16+q*4+3]) : "v"(w4.w));
    }
  }

  __shared__ float hs[2][H];          // double-buffered h
  __shared__ float hstage[2][8];      // per-WG publish staging

  for (int s=0; s<SEQL; ++s){
    const int b = s & 1;
    const int t = dir ? (SEQL-1-s) : s;
    const float* gxt = gx + (size_t)t*G3;
    // h-independent work before the wait: gx loads + AGPR->VGPR weight pulls
    float g0 = gxt[ia], g1 = gxt[H+ia], g2 = gxt[2*H+ia];
    float wr[48];
    #pragma unroll
    for (int i=0; i<48; ++i)
      asm volatile("v_accvgpr_read_b32 %0, %1" : "=v"(wr[i]) : "a"(wa[i]));

    // 1) discovery: wave0 lanes 0..7 spin on sub-counters of step s-1
    if (s > 0 && wv == 0 && lane < 8){
      const int* cp = ctr + ((size_t)(s-1)*8 + lane)*16;
      while (ld_ctr(cp) < 16) { }
    }
    __syncthreads();                  // counters confirmed -> h[s-1] complete

    // 2) one-shot h read (4KB, 256 lanes x 16B)
    if (tid < 256){
      float4 v = (s == 0) ? make_float4(0.f,0.f,0.f,0.f)
                          : ld_cohere4(hbuf + (size_t)(s-1)*H + tid*4);
      *(float4*)&hs[b][tid*4] = v;
    }
    __syncthreads();                  // hs ready

    // 3) compute
    float hv[16];
    #pragma unroll
    for (int q=0; q<4; ++q){
      float4 hq = *(const float4*)&hs[b][q*256 + lane*4];
      hv[q*4+0]=hq.x; hv[q*4+1]=hq.y; hv[q*4+2]=hq.z; hv[q*4+3]=hq.w;
    }
    float dots[3];
    #pragma unroll
    for (int rr=0; rr<3; ++rr){
      float acc = 0.f;
      #pragma unroll
      for (int m=0; m<16; ++m) acc = fmaf(wr[rr*16+m], hv[m], acc);
      #pragma unroll
      for (int off=32; off>0; off>>=1) acc += __shfl_xor(acc, off);
      dots[rr] = acc + bias[rr];
    }

    const float hp = hs[b][ia];
    float r = sigmoidf_(g0 + dots[0]);
    float z = sigmoidf_(g1 + dots[1]);
    float n = tanhf    (g2 + r*dots[2]);
    float hn = (1.f - z)*n + z*hp;

    if (lane == 0){
      hstage[b][wv] = hn;
      out[(size_t)t*2048 + dir*H + ia] = hn;
      if (s == SEQL-1){
        const size_t base = (size_t)SEQL*2048;
        out[base + dir*H + ia]        = hn;   // hidden
        out[base + 2048 + dir*H + ia] = hn;   // projected_output
      }
    }
    __syncthreads();                  // hstage ready

    // 4) publish: one thread stores the WG's 32B chunk + increments sub-counter
    if (tid == 0){
      float* dst = hbuf + (size_t)s*H + i0;
      st_cohere2(dst + 0, *(float2*)&hstage[b][0]);
      st_cohere2(dst + 2, *(float2*)&hstage[b][2]);
      st_cohere2(dst + 4, *(float2*)&hstage[b][4]);
      st_cohere2(dst + 6, *(float2*)&hstage[b][6]);
      asm volatile("s_waitcnt vmcnt(0)" ::: "memory");
      __hip_atomic_fetch_add(ctr + ((size_t)s*8 + (d & 7))*16, 1,
                             __ATOMIC_RELAXED, __HIP_MEMORY_SCOPE_AGENT);
    }
  }
}

extern "C" void kernel_launch(void* const* d_in, const int* in_sizes, int n_in,
                              void* d_out, int out_size, void* d_ws, size_t ws_size,
                              hipStream_t stream)
{
  const int*   ids  = (const int*)  d_in[0];
  const float* emb  = (const float*)d_in[1];
  const float* WihF = (const float*)d_in[2];
  const float* WhhF = (const float*)d_in[3];
  const float* bihF = (const float*)d_in[4];
  const float* bhhF = (const float*)d_in[5];
  const float* WihR = (const float*)d_in[6];
  const float* WhhR = (const float*)d_in[7];
  const float* bihR = (const float*)d_in[8];
  const float* bhhR = (const float*)d_in[9];
  float* out = (float*)d_out;
  float* ws  = (float*)d_ws;

  float* embeds = ws;                       // 2048*1024
  float* gxF    = embeds + (size_t)SEQL*H;  // 2048*3072
  float* gxR    = gxF + (size_t)SEQL*G3;    // 2048*3072
  float* hF     = gxR + (size_t)SEQL*G3;    // 2048*1024
  float* hR     = hF + (size_t)SEQL*H;      // 2048*1024
  int*   ctrF   = (int*)(hR + (size_t)SEQL*H);  // 2048*8*16 ints
  int*   ctrR   = ctrF + (size_t)SEQL*8*16;     // 2048*8*16 ints

  // zero both counter regions: 2*2048*8*16 = 524288 ints = 131072 int4
  init_zero<<<512, 256, 0, stream>>>(ctrF, 131072);
  embed_kernel<<<SEQL, 256, 0, stream>>>(ids, emb, embeds);
  dim3 gg(96, 32);
  gemm_kernel<<<gg, 256, 0, stream>>>(embeds, WihF, WihR, bihF, bihR, gxF, gxR);
  scan_kernel<<<256, 512, 0, stream>>>(gxF, gxR, WhhF, WhhR, bhhF, bhhR,
                                       hF, hR, ctrF, ctrR, out);
}